// Round 10
// baseline (205.244 us; speedup 1.0000x reference)
//
#include <hip/hip_runtime.h>
#include <hip/hip_bf16.h>

// CausalGraphLayer: out = [D^-1/2 (A+I) D^-1/2 (x W) + b] @ softmax(CA)
// Folded: M = W @ softmax(CA); bs = b @ softmax(CA);
//         z[i] = dinv[i] * (x[i] @ M)   (stored bf16)
//         out[d] = dinv[d] * (z[d] + sum_{(s,d) in E} z[s]) + bs
// N = 100000, E = 1600000, D = 64.
//
// Round 10: (1) gather v3 — 2 edges per uint load (wave covers 2 z-rows per
// load instr), unroll 8, shfl_xor(32) merge. (2) bin BIN_TILE 8192->2048:
// 196 blocks was <1 block/CU (no TLP to hide LDS-atomic/scatter latency).
// Arena pipeline otherwise = round-9 proven. WS ~24 MiB.

#define D 64
#define BSHIFT 7
#define BNODES 128       // nodes per bucket
#define ARENA_CAP 3072   // arena slots per bucket (mean 2046, +22 sigma)
#define REBIN_CAP 8192   // rebin LDS staging
#define BIN_TILE 2048    // bin edges per block (782 blocks ~ 3/CU)

// f32 -> bf16 (round to nearest even)
__device__ __forceinline__ unsigned short f2bf(float f) {
    union { float f; unsigned int u; } c;
    c.f = f;
    unsigned int u = c.u;
    u += 0x7fffu + ((u >> 16) & 1u);
    return (unsigned short)(u >> 16);
}
__device__ __forceinline__ float bf2f(unsigned short r) {
    union { unsigned int u; float f; } c;
    c.u = ((unsigned int)r) << 16;
    return c.f;
}
// low/high bf16 of a packed uint -> f32
__device__ __forceinline__ float bflo(unsigned int u) {
    union { unsigned int u; float f; } c;
    c.u = u << 16;
    return c.f;
}
__device__ __forceinline__ float bfhi(unsigned int u) {
    union { unsigned int u; float f; } c;
    c.u = u & 0xffff0000u;
    return c.f;
}

// ---------------- K1: S = softmax(A); M = W@S; bs = b@S; init cursors -------
__global__ __launch_bounds__(256) void prep_kernel(const float* __restrict__ W,
                                                   const float* __restrict__ b,
                                                   const float* __restrict__ A,
                                                   float* __restrict__ M,
                                                   float* __restrict__ bs,
                                                   int* __restrict__ cursor, int nbuck) {
    __shared__ float S[D * D];
    int t = threadIdx.x;
    int gidx = blockIdx.x * 256 + t;
    if (gidx < nbuck) cursor[gidx] = gidx * ARENA_CAP;  // arena base
    if (t < D) {
        float mx = -1e30f;
        for (int j = 0; j < D; j++) mx = fmaxf(mx, A[t * D + j]);
        float sum = 0.f;
        for (int j = 0; j < D; j++) {
            float v = __expf(A[t * D + j] - mx);
            S[t * D + j] = v;
            sum += v;
        }
        float inv = 1.f / sum;
        for (int j = 0; j < D; j++) S[t * D + j] *= inv;
    }
    __syncthreads();
    int k = blockIdx.x * 4 + (t >> 6);
    int j = t & 63;
    float acc = 0.f;
    for (int d = 0; d < D; d++) acc += W[k * D + d] * S[d * D + j];
    M[k * D + j] = acc;
    if (blockIdx.x == 0 && t < D) {
        float a2 = 0.f;
        for (int d = 0; d < D; d++) a2 += b[d] * S[d * D + t];
        bs[t] = a2;
    }
}

// ---------------- K2: bin edges (packed) into bucket arenas ----------------
__global__ __launch_bounds__(256) void bin_kernel(const int* __restrict__ src,
                                                  const int* __restrict__ dst,
                                                  int* __restrict__ cursor,
                                                  int* __restrict__ binned, int E) {
    __shared__ int h[1024];
    __shared__ int pbuf[BIN_TILE];
    __shared__ unsigned short bb[BIN_TILE];
    int t = threadIdx.x;
    for (int i = t; i < 1024; i += 256) h[i] = 0;
    __syncthreads();
    int base = blockIdx.x * BIN_TILE;
    int cnt = min(E - base, BIN_TILE);
    for (int i = t; i < cnt; i += 256) {
        int s = src[base + i], d = dst[base + i];
        int bk = (d >> BSHIFT) & 1023;
        pbuf[i] = (s << BSHIFT) | (d & (BNODES - 1));  // packed: src<<7 | dlocal
        bb[i] = (unsigned short)bk;
        atomicAdd(&h[bk], 1);
    }
    __syncthreads();
    for (int b = t; b < 1024; b += 256) {
        int c = h[b];
        if (c) h[b] = atomicAdd(&cursor[b], c);  // h[b] := global write base
    }
    __syncthreads();
    for (int i = t; i < cnt; i += 256) {
        int pos = atomicAdd(&h[bb[i]], 1);
        binned[pos] = pbuf[i];
    }
}

// ---------------- K3: in-bucket node sort -> rowstart/rowend/dinv/src csr ---
__global__ __launch_bounds__(256) void rebin_kernel(int* __restrict__ binned,
                                                    const int* __restrict__ cursor,
                                                    int* __restrict__ rowstart,
                                                    int* __restrict__ rowend,
                                                    float* __restrict__ dinv, int N) {
    __shared__ int buf[REBIN_CAP];
    __shared__ int h[BNODES];
    __shared__ int sc[BNODES];
    __shared__ int cur[BNODES];
    int t = threadIdx.x;
    int b = blockIdx.x;
    int s = b * ARENA_CAP;
    int cnt = cursor[b] - s;  // edges actually in this bucket
    if (cnt > REBIN_CAP) cnt = REBIN_CAP;  // never binds
    if (t < BNODES) h[t] = 0;
    __syncthreads();
    for (int i = t; i < cnt; i += 256) {
        int p = binned[s + i];
        buf[i] = p;
        atomicAdd(&h[p & (BNODES - 1)], 1);
    }
    __syncthreads();
    if (t < BNODES) sc[t] = h[t];
    __syncthreads();
    for (int off = 1; off < BNODES; off <<= 1) {
        int u = (t < BNODES && t >= off) ? sc[t - off] : 0;
        __syncthreads();
        if (t < BNODES) sc[t] += u;
        __syncthreads();
    }
    if (t < BNODES) {
        int ex = sc[t] - h[t];  // exclusive prefix
        cur[t] = ex;
        int node = (b << BSHIFT) + t;
        if (node < N) {
            rowstart[node] = s + ex;
            rowend[node] = s + sc[t];
            dinv[node] = rsqrtf((float)(h[t] + 1));
        }
    }
    __syncthreads();
    for (int i = t; i < cnt; i += 256) {
        int p = buf[i];
        int pos = atomicAdd(&cur[p & (BNODES - 1)], 1);
        binned[s + pos] = (int)((unsigned)p >> BSHIFT);  // plain src index
    }
}

// ---------------- K4: z = dinv * (x @ M), stored bf16 ----------------
__global__ __launch_bounds__(256) void zmat_kernel(const float* __restrict__ x,
                                                   const float* __restrict__ M,
                                                   const float* __restrict__ dinv,
                                                   unsigned short* __restrict__ zbf, int n) {
    __shared__ float Ms[D * D];
    __shared__ float xs[16][D + 1];
    int t = threadIdx.x;
    for (int i = t; i < (D * D) / 4; i += 256)
        ((float4*)Ms)[i] = ((const float4*)M)[i];
    int row0 = blockIdx.x * 16;
    for (int i = t; i < 16 * D; i += 256) {
        int r = i >> 6, c = i & 63;
        xs[r][c] = (row0 + r < n) ? x[(size_t)(row0 + r) * D + c] : 0.f;
    }
    __syncthreads();
    int r = t >> 4;
    int jg = (t & 15) << 2;
    float4 acc = {0.f, 0.f, 0.f, 0.f};
#pragma unroll
    for (int k = 0; k < D; k++) {
        float xv = xs[r][k];
        float4 m = *(const float4*)&Ms[k * D + jg];
        acc.x += xv * m.x;
        acc.y += xv * m.y;
        acc.z += xv * m.z;
        acc.w += xv * m.w;
    }
    int row = row0 + r;
    if (row < n) {
        float di = dinv[row];
        ushort4 res;
        res.x = f2bf(di * acc.x);
        res.y = f2bf(di * acc.y);
        res.z = f2bf(di * acc.z);
        res.w = f2bf(di * acc.w);
        *(ushort4*)&zbf[(size_t)row * D + jg] = res;
    }
}

// ---------------- K5: gather v3 — 2 edges per uint load ----------------
// lane = (g = lane>>5: edge subgroup, c = lane&31: column pair -> cols 2c,2c+1)
// One uint load/lane = 2 bf16; a wave covers 2 full z-rows per instruction.
__global__ __launch_bounds__(256) void gather_kernel(const unsigned short* __restrict__ zbf,
                                                     const int* __restrict__ csr,
                                                     const int* __restrict__ rowstart,
                                                     const int* __restrict__ rowend,
                                                     const float* __restrict__ dinv,
                                                     const float* __restrict__ bs,
                                                     float* __restrict__ out, int n) {
    int node = blockIdx.x * 4 + (threadIdx.x >> 6);
    if (node >= n) return;
    int lane = threadIdx.x & 63;
    int g = lane >> 5;
    int c = lane & 31;
    int start = rowstart[node];
    int end = rowend[node];
    float a0 = 0.f, a1 = 0.f, a2 = 0.f, a3 = 0.f;
    int e = start;
    while (e < end) {
        int cnt = min(end - e, 64);
        int sreg = (lane < cnt) ? csr[e + lane] : 0;
        int k = 0;
        for (; k + 7 < cnt; k += 8) {  // 8 edges / iter, 4 loads in flight
            int p0 = __shfl(sreg, k + g);
            int p1 = __shfl(sreg, k + 2 + g);
            int p2 = __shfl(sreg, k + 4 + g);
            int p3 = __shfl(sreg, k + 6 + g);
            unsigned u0 = *(const unsigned*)&zbf[(size_t)p0 * D + 2 * c];
            unsigned u1 = *(const unsigned*)&zbf[(size_t)p1 * D + 2 * c];
            unsigned u2 = *(const unsigned*)&zbf[(size_t)p2 * D + 2 * c];
            unsigned u3 = *(const unsigned*)&zbf[(size_t)p3 * D + 2 * c];
            a0 += bflo(u0); a1 += bfhi(u0);
            a2 += bflo(u1); a3 += bfhi(u1);
            a0 += bflo(u2); a1 += bfhi(u2);
            a2 += bflo(u3); a3 += bfhi(u3);
        }
        for (; k + 1 < cnt; k += 2) {  // pair tail: g=0 edge k, g=1 edge k+1
            int p = __shfl(sreg, k + g);
            unsigned u = *(const unsigned*)&zbf[(size_t)p * D + 2 * c];
            a0 += bflo(u); a1 += bfhi(u);
        }
        if (k < cnt) {  // odd last edge: broadcast, g==0 accumulates
            int p = __shfl(sreg, k);
            unsigned u = *(const unsigned*)&zbf[(size_t)p * D + 2 * c];
            if (g == 0) { a0 += bflo(u); a1 += bfhi(u); }
        }
        e += cnt;
    }
    a0 += a2; a1 += a3;
    a0 += __shfl_xor(a0, 32);  // merge g halves
    a1 += __shfl_xor(a1, 32);
    if (lane < 32) {
        unsigned uz = *(const unsigned*)&zbf[(size_t)node * D + 2 * c];  // self loop
        float2 bb = ((const float2*)bs)[c];
        float di = dinv[node];
        float2 o;
        o.x = di * (a0 + bflo(uz)) + bb.x;
        o.y = di * (a1 + bfhi(uz)) + bb.y;
        ((float2*)&out[(size_t)node * D])[c] = o;
    }
}

extern "C" void kernel_launch(void* const* d_in, const int* in_sizes, int n_in,
                              void* d_out, int out_size, void* d_ws, size_t ws_size,
                              hipStream_t stream) {
    const float* x = (const float*)d_in[0];
    const int* ei = (const int*)d_in[1];
    const float* W = (const float*)d_in[2];
    const float* b = (const float*)d_in[3];
    const float* A = (const float*)d_in[4];

    const int N = in_sizes[0] / D;
    const int E = in_sizes[1] / 2;
    const int* src = ei;
    const int* dst = ei + E;
    const int NBUCK = (N + BNODES - 1) >> BSHIFT;  // 782; must be <=1024

    char* ws = (char*)d_ws;
    size_t off = 0;
    auto alloc = [&](size_t bytes) -> char* {
        char* p = ws + off;
        off = (off + bytes + 255) & ~(size_t)255;
        return p;
    };
    int* cursor = (int*)alloc((size_t)NBUCK * 4);
    float* dinv = (float*)alloc((size_t)N * 4);
    float* M = (float*)alloc((size_t)D * D * 4);
    float* bs = (float*)alloc((size_t)D * 4);
    int* binned = (int*)alloc((size_t)NBUCK * ARENA_CAP * 4);  // 9.6 MB arena
    int* rowstart = (int*)alloc((size_t)N * 4);
    int* rowend = (int*)alloc((size_t)N * 4);
    unsigned short* zbf = (unsigned short*)alloc((size_t)N * D * 2);
    (void)ws_size;  // total ~24 MiB (< 32.06 MiB proven safe)

    prep_kernel<<<16, 256, 0, stream>>>(W, b, A, M, bs, cursor, NBUCK);
    bin_kernel<<<(E + BIN_TILE - 1) / BIN_TILE, 256, 0, stream>>>(src, dst, cursor, binned, E);
    rebin_kernel<<<NBUCK, 256, 0, stream>>>(binned, cursor, rowstart, rowend, dinv, N);
    zmat_kernel<<<(N + 15) / 16, 256, 0, stream>>>(x, M, dinv, zbf, N);
    gather_kernel<<<(N + 3) / 4, 256, 0, stream>>>(zbf, binned, rowstart, rowend, dinv, bs, (float*)d_out, N);
}

// Round 11
// 198.332 us; speedup vs baseline: 1.0348x; 1.0348x over previous
//
#include <hip/hip_runtime.h>
#include <hip/hip_bf16.h>

// CausalGraphLayer: out = [D^-1/2 (A+I) D^-1/2 (x W) + b] @ softmax(CA)
// Folded: M = W @ softmax(CA); bs = b @ softmax(CA);
//         z[i] = dinv[i] * (x[i] @ M)   (stored bf16)
//         out[d] = dinv[d] * (z[d] + sum_{(s,d) in E} z[s]) + bs
// N = 100000, E = 1600000, D = 64.
//
// Round 11: (1) bin reverted to BIN_TILE=8192 (2048 quadrupled cursor-atomic
// contention, +8us) and widened to 512 threads (grid=196 <1/CU; waves are the
// only TLP available). (2) rebin+zmat FUSED: block sorts bucket b's edges,
// then computes z for its 128 contiguous nodes (M in LDS, dinv from LDS).
// 4 dispatches: prep -> bin -> rebin_zmat -> gather. gather = round-10 proven.

#define D 64
#define BSHIFT 7
#define BNODES 128       // nodes per bucket
#define ARENA_CAP 3072   // arena slots per bucket (mean 2046, +22 sigma)
#define BIN_TILE 8192    // bin edges per block (196 blocks)

// f32 -> bf16 (round to nearest even)
__device__ __forceinline__ unsigned short f2bf(float f) {
    union { float f; unsigned int u; } c;
    c.f = f;
    unsigned int u = c.u;
    u += 0x7fffu + ((u >> 16) & 1u);
    return (unsigned short)(u >> 16);
}
// low/high bf16 of a packed uint -> f32
__device__ __forceinline__ float bflo(unsigned int u) {
    union { unsigned int u; float f; } c;
    c.u = u << 16;
    return c.f;
}
__device__ __forceinline__ float bfhi(unsigned int u) {
    union { unsigned int u; float f; } c;
    c.u = u & 0xffff0000u;
    return c.f;
}

// ---------------- K1: S = softmax(A); M = W@S; bs = b@S; init cursors -------
__global__ __launch_bounds__(256) void prep_kernel(const float* __restrict__ W,
                                                   const float* __restrict__ b,
                                                   const float* __restrict__ A,
                                                   float* __restrict__ M,
                                                   float* __restrict__ bs,
                                                   int* __restrict__ cursor, int nbuck) {
    __shared__ float S[D * D];
    int t = threadIdx.x;
    int gidx = blockIdx.x * 256 + t;
    if (gidx < nbuck) cursor[gidx] = gidx * ARENA_CAP;  // arena base
    if (t < D) {
        float mx = -1e30f;
        for (int j = 0; j < D; j++) mx = fmaxf(mx, A[t * D + j]);
        float sum = 0.f;
        for (int j = 0; j < D; j++) {
            float v = __expf(A[t * D + j] - mx);
            S[t * D + j] = v;
            sum += v;
        }
        float inv = 1.f / sum;
        for (int j = 0; j < D; j++) S[t * D + j] *= inv;
    }
    __syncthreads();
    int k = blockIdx.x * 4 + (t >> 6);
    int j = t & 63;
    float acc = 0.f;
    for (int d = 0; d < D; d++) acc += W[k * D + d] * S[d * D + j];
    M[k * D + j] = acc;
    if (blockIdx.x == 0 && t < D) {
        float a2 = 0.f;
        for (int d = 0; d < D; d++) a2 += b[d] * S[d * D + t];
        bs[t] = a2;
    }
}

// ---------------- K2: bin edges (packed) into bucket arenas ----------------
// 512 threads: grid is 196 blocks (<1/CU) so block-level TLP is all we have.
__global__ __launch_bounds__(512) void bin_kernel(const int* __restrict__ src,
                                                  const int* __restrict__ dst,
                                                  int* __restrict__ cursor,
                                                  int* __restrict__ binned, int E) {
    __shared__ int h[1024];
    __shared__ int pbuf[BIN_TILE];
    __shared__ unsigned short bb[BIN_TILE];
    int t = threadIdx.x;
    for (int i = t; i < 1024; i += 512) h[i] = 0;
    __syncthreads();
    int base = blockIdx.x * BIN_TILE;
    int cnt = min(E - base, BIN_TILE);
    for (int i = t; i < cnt; i += 512) {
        int s = src[base + i], d = dst[base + i];
        int bk = (d >> BSHIFT) & 1023;
        pbuf[i] = (s << BSHIFT) | (d & (BNODES - 1));  // packed: src<<7 | dlocal
        bb[i] = (unsigned short)bk;
        atomicAdd(&h[bk], 1);
    }
    __syncthreads();
    for (int b = t; b < 1024; b += 512) {
        int c = h[b];
        if (c) h[b] = atomicAdd(&cursor[b], c);  // h[b] := global write base
    }
    __syncthreads();
    for (int i = t; i < cnt; i += 512) {
        int pos = atomicAdd(&h[bb[i]], 1);
        binned[pos] = pbuf[i];
    }
}

// ---------------- K3: FUSED in-bucket sort + z for the bucket's nodes -------
// Phase A (rebin): stage packed segment, histogram dlocal, scan, write back
//   node-sorted plain src; emit rowstart/rowend/dinv (dinv also kept in LDS).
// Phase B (zmat): z[node] = dinv[node] * (x[node] @ M) for the 128 contiguous
//   nodes of this bucket, 8 chunks of 16 rows; inner loop = proven zmat code.
__global__ __launch_bounds__(256) void rebin_zmat_kernel(const float* __restrict__ x,
                                                         const float* __restrict__ M,
                                                         int* __restrict__ binned,
                                                         const int* __restrict__ cursor,
                                                         int* __restrict__ rowstart,
                                                         int* __restrict__ rowend,
                                                         float* __restrict__ dinv,
                                                         unsigned short* __restrict__ zbf,
                                                         int N) {
    __shared__ int buf[ARENA_CAP];    // 12 KB
    __shared__ float Ms[D * D];       // 16 KB
    __shared__ float xs[16][D + 1];   // 4.2 KB
    __shared__ float dv[BNODES];
    __shared__ int h[BNODES];
    __shared__ int sc[BNODES];
    __shared__ int cur[BNODES];
    int t = threadIdx.x;
    int b = blockIdx.x;
    int s = b * ARENA_CAP;
    int cnt = cursor[b] - s;
    if (cnt > ARENA_CAP) cnt = ARENA_CAP;  // by construction never binds
    // stage M while sorting (used only after the post-scatter barrier)
    for (int i = t; i < (D * D) / 4; i += 256)
        ((float4*)Ms)[i] = ((const float4*)M)[i];
    if (t < BNODES) h[t] = 0;
    __syncthreads();
    for (int i = t; i < cnt; i += 256) {
        int p = binned[s + i];
        buf[i] = p;
        atomicAdd(&h[p & (BNODES - 1)], 1);
    }
    __syncthreads();
    if (t < BNODES) sc[t] = h[t];
    __syncthreads();
    for (int off = 1; off < BNODES; off <<= 1) {
        int u = (t < BNODES && t >= off) ? sc[t - off] : 0;
        __syncthreads();
        if (t < BNODES) sc[t] += u;
        __syncthreads();
    }
    if (t < BNODES) {
        int ex = sc[t] - h[t];  // exclusive prefix
        cur[t] = ex;
        float di = rsqrtf((float)(h[t] + 1));
        dv[t] = di;
        int node = (b << BSHIFT) + t;
        if (node < N) {
            rowstart[node] = s + ex;
            rowend[node] = s + sc[t];
            dinv[node] = di;
        }
    }
    __syncthreads();
    for (int i = t; i < cnt; i += 256) {
        int p = buf[i];
        int pos = atomicAdd(&cur[p & (BNODES - 1)], 1);
        binned[s + pos] = (int)((unsigned)p >> BSHIFT);  // plain src index
    }
    // ---- Phase B: z for nodes [b*128, b*128+128) in 8 chunks of 16 rows ----
    for (int rc = 0; rc < 8; rc++) {
        __syncthreads();  // xs reuse (and first iter: Ms/sort complete)
        int row0 = (b << BSHIFT) + rc * 16;
        for (int i = t; i < 16 * D; i += 256) {
            int r = i >> 6, c = i & 63;
            xs[r][c] = (row0 + r < N) ? x[(size_t)(row0 + r) * D + c] : 0.f;
        }
        __syncthreads();
        int r = t >> 4;
        int jg = (t & 15) << 2;
        float4 acc = {0.f, 0.f, 0.f, 0.f};
#pragma unroll
        for (int k = 0; k < D; k++) {
            float xv = xs[r][k];
            float4 m = *(const float4*)&Ms[k * D + jg];
            acc.x += xv * m.x;
            acc.y += xv * m.y;
            acc.z += xv * m.z;
            acc.w += xv * m.w;
        }
        int row = row0 + r;
        if (row < N) {
            float di = dv[rc * 16 + r];
            ushort4 res;
            res.x = f2bf(di * acc.x);
            res.y = f2bf(di * acc.y);
            res.z = f2bf(di * acc.z);
            res.w = f2bf(di * acc.w);
            *(ushort4*)&zbf[(size_t)row * D + jg] = res;
        }
    }
}

// ---------------- K4: gather v3 (round-10 proven, verbatim) ----------------
__global__ __launch_bounds__(256) void gather_kernel(const unsigned short* __restrict__ zbf,
                                                     const int* __restrict__ csr,
                                                     const int* __restrict__ rowstart,
                                                     const int* __restrict__ rowend,
                                                     const float* __restrict__ dinv,
                                                     const float* __restrict__ bs,
                                                     float* __restrict__ out, int n) {
    int node = blockIdx.x * 4 + (threadIdx.x >> 6);
    if (node >= n) return;
    int lane = threadIdx.x & 63;
    int g = lane >> 5;
    int c = lane & 31;
    int start = rowstart[node];
    int end = rowend[node];
    float a0 = 0.f, a1 = 0.f, a2 = 0.f, a3 = 0.f;
    int e = start;
    while (e < end) {
        int cnt = min(end - e, 64);
        int sreg = (lane < cnt) ? csr[e + lane] : 0;
        int k = 0;
        for (; k + 7 < cnt; k += 8) {  // 8 edges / iter, 4 loads in flight
            int p0 = __shfl(sreg, k + g);
            int p1 = __shfl(sreg, k + 2 + g);
            int p2 = __shfl(sreg, k + 4 + g);
            int p3 = __shfl(sreg, k + 6 + g);
            unsigned u0 = *(const unsigned*)&zbf[(size_t)p0 * D + 2 * c];
            unsigned u1 = *(const unsigned*)&zbf[(size_t)p1 * D + 2 * c];
            unsigned u2 = *(const unsigned*)&zbf[(size_t)p2 * D + 2 * c];
            unsigned u3 = *(const unsigned*)&zbf[(size_t)p3 * D + 2 * c];
            a0 += bflo(u0); a1 += bfhi(u0);
            a2 += bflo(u1); a3 += bfhi(u1);
            a0 += bflo(u2); a1 += bfhi(u2);
            a2 += bflo(u3); a3 += bfhi(u3);
        }
        for (; k + 1 < cnt; k += 2) {  // pair tail: g=0 edge k, g=1 edge k+1
            int p = __shfl(sreg, k + g);
            unsigned u = *(const unsigned*)&zbf[(size_t)p * D + 2 * c];
            a0 += bflo(u); a1 += bfhi(u);
        }
        if (k < cnt) {  // odd last edge: broadcast, g==0 accumulates
            int p = __shfl(sreg, k);
            unsigned u = *(const unsigned*)&zbf[(size_t)p * D + 2 * c];
            if (g == 0) { a0 += bflo(u); a1 += bfhi(u); }
        }
        e += cnt;
    }
    a0 += a2; a1 += a3;
    a0 += __shfl_xor(a0, 32);  // merge g halves
    a1 += __shfl_xor(a1, 32);
    if (lane < 32) {
        unsigned uz = *(const unsigned*)&zbf[(size_t)node * D + 2 * c];  // self loop
        float2 bb = ((const float2*)bs)[c];
        float di = dinv[node];
        float2 o;
        o.x = di * (a0 + bflo(uz)) + bb.x;
        o.y = di * (a1 + bfhi(uz)) + bb.y;
        ((float2*)&out[(size_t)node * D])[c] = o;
    }
}

extern "C" void kernel_launch(void* const* d_in, const int* in_sizes, int n_in,
                              void* d_out, int out_size, void* d_ws, size_t ws_size,
                              hipStream_t stream) {
    const float* x = (const float*)d_in[0];
    const int* ei = (const int*)d_in[1];
    const float* W = (const float*)d_in[2];
    const float* b = (const float*)d_in[3];
    const float* A = (const float*)d_in[4];

    const int N = in_sizes[0] / D;
    const int E = in_sizes[1] / 2;
    const int* src = ei;
    const int* dst = ei + E;
    const int NBUCK = (N + BNODES - 1) >> BSHIFT;  // 782; must be <=1024

    char* ws = (char*)d_ws;
    size_t off = 0;
    auto alloc = [&](size_t bytes) -> char* {
        char* p = ws + off;
        off = (off + bytes + 255) & ~(size_t)255;
        return p;
    };
    int* cursor = (int*)alloc((size_t)NBUCK * 4);
    float* dinv = (float*)alloc((size_t)N * 4);
    float* M = (float*)alloc((size_t)D * D * 4);
    float* bs = (float*)alloc((size_t)D * 4);
    int* binned = (int*)alloc((size_t)NBUCK * ARENA_CAP * 4);  // 9.6 MB arena
    int* rowstart = (int*)alloc((size_t)N * 4);
    int* rowend = (int*)alloc((size_t)N * 4);
    unsigned short* zbf = (unsigned short*)alloc((size_t)N * D * 2);
    (void)ws_size;  // total ~24 MiB (< 32.06 MiB proven safe)

    prep_kernel<<<16, 256, 0, stream>>>(W, b, A, M, bs, cursor, NBUCK);
    bin_kernel<<<(E + BIN_TILE - 1) / BIN_TILE, 512, 0, stream>>>(src, dst, cursor, binned, E);
    rebin_zmat_kernel<<<NBUCK, 256, 0, stream>>>(x, M, binned, cursor, rowstart, rowend, dinv, zbf, N);
    gather_kernel<<<(N + 3) / 4, 256, 0, stream>>>(zbf, binned, rowstart, rowend, dinv, bs, (float*)d_out, N);
}

// Round 12
// 195.363 us; speedup vs baseline: 1.0506x; 1.0152x over previous
//
#include <hip/hip_runtime.h>
#include <hip/hip_bf16.h>

// CausalGraphLayer: out = [D^-1/2 (A+I) D^-1/2 (x W) + b] @ softmax(CA)
// Folded: M = W @ softmax(CA); bs = b @ softmax(CA);
//         z[i] = dinv[i] * (x[i] @ M)   (stored bf16)
//         out[d] = dinv[d] * (z[d] + sum_{(s,d) in E} z[s]) + bs
// N = 100000, E = 1600000, D = 64.
//
// Round 12: (1) prep v2 — wave-per-row softmax via shfl_xor reductions
// (old version: 64 threads each running three serial 64-iter scalar loops
// at 16 blocks = latency-serialized). (2) bin v3 — register staging
// (round-4-proven pattern, 16 edges/thread x 512 thr), no pbuf/bb LDS
// round-trip. rebin_zmat + gather = round-11 proven verbatim.

#define D 64
#define BSHIFT 7
#define BNODES 128       // nodes per bucket
#define ARENA_CAP 3072   // arena slots per bucket (mean 2046, +22 sigma)
#define BIN_TILE 8192    // bin edges per block (196 blocks)

// f32 -> bf16 (round to nearest even)
__device__ __forceinline__ unsigned short f2bf(float f) {
    union { float f; unsigned int u; } c;
    c.f = f;
    unsigned int u = c.u;
    u += 0x7fffu + ((u >> 16) & 1u);
    return (unsigned short)(u >> 16);
}
// low/high bf16 of a packed uint -> f32
__device__ __forceinline__ float bflo(unsigned int u) {
    union { unsigned int u; float f; } c;
    c.u = u << 16;
    return c.f;
}
__device__ __forceinline__ float bfhi(unsigned int u) {
    union { unsigned int u; float f; } c;
    c.u = u & 0xffff0000u;
    return c.f;
}

// ---------------- K1: prep v2 — S = softmax(A); M = W@S; bs = b@S -----------
// 4 waves x 16 rows: lane j holds A[r][j]; max/sum via shfl_xor butterflies.
__global__ __launch_bounds__(256) void prep_kernel(const float* __restrict__ W,
                                                   const float* __restrict__ b,
                                                   const float* __restrict__ A,
                                                   float* __restrict__ M,
                                                   float* __restrict__ bs,
                                                   int* __restrict__ cursor, int nbuck) {
    __shared__ float S[D * D];
    int t = threadIdx.x;
    int gidx = blockIdx.x * 256 + t;
    if (gidx < nbuck) cursor[gidx] = gidx * ARENA_CAP;  // arena base
    int wv = t >> 6, lane = t & 63;
#pragma unroll 4
    for (int rr = 0; rr < 16; rr++) {
        int r = wv * 16 + rr;
        float a = A[r * D + lane];
        float m = a;
        for (int off = 32; off; off >>= 1) m = fmaxf(m, __shfl_xor(m, off));
        float p = __expf(a - m);
        float ssum = p;
        for (int off = 32; off; off >>= 1) ssum += __shfl_xor(ssum, off);
        S[r * D + lane] = p / ssum;
    }
    __syncthreads();
    int k = blockIdx.x * 4 + wv;  // M row (wave-uniform)
    float acc = 0.f;
    for (int d2 = 0; d2 < D; d2++) acc += W[k * D + d2] * S[d2 * D + lane];
    M[k * D + lane] = acc;
    if (blockIdx.x == 0 && t < D) {
        float a2 = 0.f;
        for (int d2 = 0; d2 < D; d2++) a2 += b[d2] * S[d2 * D + t];
        bs[t] = a2;
    }
}

// ---------------- K2: bin v3 — register staging, 16 edges/thread ------------
__global__ __launch_bounds__(512) void bin_kernel(const int* __restrict__ src,
                                                  const int* __restrict__ dst,
                                                  int* __restrict__ cursor,
                                                  int* __restrict__ binned, int E) {
    __shared__ int h[1024];
    int t = threadIdx.x;
    for (int i = t; i < 1024; i += 512) h[i] = 0;
    __syncthreads();
    int base = blockIdx.x * BIN_TILE;
    int pv[16], bk[16], rv[16];
#pragma unroll
    for (int k = 0; k < 16; k++) {
        int e = base + k * 512 + t;
        if (e < E) {
            int s = src[e], d = dst[e];
            bk[k] = (d >> BSHIFT) & 1023;
            pv[k] = (s << BSHIFT) | (d & (BNODES - 1));  // packed: src<<7 | dlocal
            rv[k] = atomicAdd(&h[bk[k]], 1);             // rank within (block,bucket)
        }
    }
    __syncthreads();
    for (int b2 = t; b2 < 1024; b2 += 512) {
        int c = h[b2];
        if (c) h[b2] = atomicAdd(&cursor[b2], c);  // h[b2] := global write base
    }
    __syncthreads();
#pragma unroll
    for (int k = 0; k < 16; k++) {
        int e = base + k * 512 + t;
        if (e < E) binned[h[bk[k]] + rv[k]] = pv[k];
    }
}

// ---------------- K3: FUSED in-bucket sort + z (round-11 proven) ------------
__global__ __launch_bounds__(256) void rebin_zmat_kernel(const float* __restrict__ x,
                                                         const float* __restrict__ M,
                                                         int* __restrict__ binned,
                                                         const int* __restrict__ cursor,
                                                         int* __restrict__ rowstart,
                                                         int* __restrict__ rowend,
                                                         float* __restrict__ dinv,
                                                         unsigned short* __restrict__ zbf,
                                                         int N) {
    __shared__ int buf[ARENA_CAP];    // 12 KB
    __shared__ float Ms[D * D];       // 16 KB
    __shared__ float xs[16][D + 1];   // 4.2 KB
    __shared__ float dv[BNODES];
    __shared__ int h[BNODES];
    __shared__ int sc[BNODES];
    __shared__ int cur[BNODES];
    int t = threadIdx.x;
    int b = blockIdx.x;
    int s = b * ARENA_CAP;
    int cnt = cursor[b] - s;
    if (cnt > ARENA_CAP) cnt = ARENA_CAP;  // by construction never binds
    for (int i = t; i < (D * D) / 4; i += 256)
        ((float4*)Ms)[i] = ((const float4*)M)[i];
    if (t < BNODES) h[t] = 0;
    __syncthreads();
    for (int i = t; i < cnt; i += 256) {
        int p = binned[s + i];
        buf[i] = p;
        atomicAdd(&h[p & (BNODES - 1)], 1);
    }
    __syncthreads();
    if (t < BNODES) sc[t] = h[t];
    __syncthreads();
    for (int off = 1; off < BNODES; off <<= 1) {
        int u = (t < BNODES && t >= off) ? sc[t - off] : 0;
        __syncthreads();
        if (t < BNODES) sc[t] += u;
        __syncthreads();
    }
    if (t < BNODES) {
        int ex = sc[t] - h[t];  // exclusive prefix
        cur[t] = ex;
        float di = rsqrtf((float)(h[t] + 1));
        dv[t] = di;
        int node = (b << BSHIFT) + t;
        if (node < N) {
            rowstart[node] = s + ex;
            rowend[node] = s + sc[t];
            dinv[node] = di;
        }
    }
    __syncthreads();
    for (int i = t; i < cnt; i += 256) {
        int p = buf[i];
        int pos = atomicAdd(&cur[p & (BNODES - 1)], 1);
        binned[s + pos] = (int)((unsigned)p >> BSHIFT);  // plain src index
    }
    // ---- Phase B: z for nodes [b*128, b*128+128) in 8 chunks of 16 rows ----
    for (int rc = 0; rc < 8; rc++) {
        __syncthreads();
        int row0 = (b << BSHIFT) + rc * 16;
        for (int i = t; i < 16 * D; i += 256) {
            int r = i >> 6, c = i & 63;
            xs[r][c] = (row0 + r < N) ? x[(size_t)(row0 + r) * D + c] : 0.f;
        }
        __syncthreads();
        int r = t >> 4;
        int jg = (t & 15) << 2;
        float4 acc = {0.f, 0.f, 0.f, 0.f};
#pragma unroll
        for (int k = 0; k < D; k++) {
            float xv = xs[r][k];
            float4 m = *(const float4*)&Ms[k * D + jg];
            acc.x += xv * m.x;
            acc.y += xv * m.y;
            acc.z += xv * m.z;
            acc.w += xv * m.w;
        }
        int row = row0 + r;
        if (row < N) {
            float di = dv[rc * 16 + r];
            ushort4 res;
            res.x = f2bf(di * acc.x);
            res.y = f2bf(di * acc.y);
            res.z = f2bf(di * acc.z);
            res.w = f2bf(di * acc.w);
            *(ushort4*)&zbf[(size_t)row * D + jg] = res;
        }
    }
}

// ---------------- K4: gather v3 (round-10/11 proven, verbatim) --------------
__global__ __launch_bounds__(256) void gather_kernel(const unsigned short* __restrict__ zbf,
                                                     const int* __restrict__ csr,
                                                     const int* __restrict__ rowstart,
                                                     const int* __restrict__ rowend,
                                                     const float* __restrict__ dinv,
                                                     const float* __restrict__ bs,
                                                     float* __restrict__ out, int n) {
    int node = blockIdx.x * 4 + (threadIdx.x >> 6);
    if (node >= n) return;
    int lane = threadIdx.x & 63;
    int g = lane >> 5;
    int c = lane & 31;
    int start = rowstart[node];
    int end = rowend[node];
    float a0 = 0.f, a1 = 0.f, a2 = 0.f, a3 = 0.f;
    int e = start;
    while (e < end) {
        int cnt = min(end - e, 64);
        int sreg = (lane < cnt) ? csr[e + lane] : 0;
        int k = 0;
        for (; k + 7 < cnt; k += 8) {  // 8 edges / iter, 4 loads in flight
            int p0 = __shfl(sreg, k + g);
            int p1 = __shfl(sreg, k + 2 + g);
            int p2 = __shfl(sreg, k + 4 + g);
            int p3 = __shfl(sreg, k + 6 + g);
            unsigned u0 = *(const unsigned*)&zbf[(size_t)p0 * D + 2 * c];
            unsigned u1 = *(const unsigned*)&zbf[(size_t)p1 * D + 2 * c];
            unsigned u2 = *(const unsigned*)&zbf[(size_t)p2 * D + 2 * c];
            unsigned u3 = *(const unsigned*)&zbf[(size_t)p3 * D + 2 * c];
            a0 += bflo(u0); a1 += bfhi(u0);
            a2 += bflo(u1); a3 += bfhi(u1);
            a0 += bflo(u2); a1 += bfhi(u2);
            a2 += bflo(u3); a3 += bfhi(u3);
        }
        for (; k + 1 < cnt; k += 2) {  // pair tail
            int p = __shfl(sreg, k + g);
            unsigned u = *(const unsigned*)&zbf[(size_t)p * D + 2 * c];
            a0 += bflo(u); a1 += bfhi(u);
        }
        if (k < cnt) {  // odd last edge
            int p = __shfl(sreg, k);
            unsigned u = *(const unsigned*)&zbf[(size_t)p * D + 2 * c];
            if (g == 0) { a0 += bflo(u); a1 += bfhi(u); }
        }
        e += cnt;
    }
    a0 += a2; a1 += a3;
    a0 += __shfl_xor(a0, 32);  // merge g halves
    a1 += __shfl_xor(a1, 32);
    if (lane < 32) {
        unsigned uz = *(const unsigned*)&zbf[(size_t)node * D + 2 * c];  // self loop
        float2 bb = ((const float2*)bs)[c];
        float di = dinv[node];
        float2 o;
        o.x = di * (a0 + bflo(uz)) + bb.x;
        o.y = di * (a1 + bfhi(uz)) + bb.y;
        ((float2*)&out[(size_t)node * D])[c] = o;
    }
}

extern "C" void kernel_launch(void* const* d_in, const int* in_sizes, int n_in,
                              void* d_out, int out_size, void* d_ws, size_t ws_size,
                              hipStream_t stream) {
    const float* x = (const float*)d_in[0];
    const int* ei = (const int*)d_in[1];
    const float* W = (const float*)d_in[2];
    const float* b = (const float*)d_in[3];
    const float* A = (const float*)d_in[4];

    const int N = in_sizes[0] / D;
    const int E = in_sizes[1] / 2;
    const int* src = ei;
    const int* dst = ei + E;
    const int NBUCK = (N + BNODES - 1) >> BSHIFT;  // 782; must be <=1024

    char* ws = (char*)d_ws;
    size_t off = 0;
    auto alloc = [&](size_t bytes) -> char* {
        char* p = ws + off;
        off = (off + bytes + 255) & ~(size_t)255;
        return p;
    };
    int* cursor = (int*)alloc((size_t)NBUCK * 4);
    float* dinv = (float*)alloc((size_t)N * 4);
    float* M = (float*)alloc((size_t)D * D * 4);
    float* bs = (float*)alloc((size_t)D * 4);
    int* binned = (int*)alloc((size_t)NBUCK * ARENA_CAP * 4);  // 9.6 MB arena
    int* rowstart = (int*)alloc((size_t)N * 4);
    int* rowend = (int*)alloc((size_t)N * 4);
    unsigned short* zbf = (unsigned short*)alloc((size_t)N * D * 2);
    (void)ws_size;  // total ~24 MiB (< 32.06 MiB proven safe)

    prep_kernel<<<16, 256, 0, stream>>>(W, b, A, M, bs, cursor, NBUCK);
    bin_kernel<<<(E + BIN_TILE - 1) / BIN_TILE, 512, 0, stream>>>(src, dst, cursor, binned, E);
    rebin_zmat_kernel<<<NBUCK, 256, 0, stream>>>(x, M, binned, cursor, rowstart, rowend, dinv, zbf, N);
    gather_kernel<<<(N + 3) / 4, 256, 0, stream>>>(zbf, binned, rowstart, rowend, dinv, bs, (float*)d_out, N);
}